// Round 7
// baseline (4695.318 us; speedup 1.0000x reference)
//
#include <hip/hip_runtime.h>
#include <math.h>

#define EMB   1024
#define HID   1024
#define BATCH   64
#define SEQ    512

#define NBG    16   // batch groups
#define BTILE   4   // batches per group (NBG*BTILE = 64)
#define NJT    16   // j-tiles (producer WGs per batch group)
#define JTILE  64   // j per tile (NJT*JTILE = 1024)
#define NPW   128   // producer WAVES per bg (NJT * 8 waves)

#define FLAG_STRIDE 16   // one 64B line per producer-wave flag

typedef float f32x4 __attribute__((ext_vector_type(4)));

// ---------------------------------------------------------------------------
// Kernel A: x_proj GEMM.  out[(s*64+b)*1024 + n] = sum_k embeds[b][s][k]*W_ih[n][k]
//                                                  + b_ih[n] + b_hh[n]
// ---------------------------------------------------------------------------
__global__ __launch_bounds__(256) void xproj_gemm(
    const float* __restrict__ A,
    const float* __restrict__ W,
    const float* __restrict__ b_ih,
    const float* __restrict__ b_hh,
    float* __restrict__ out)
{
    __shared__ float As[16][68];
    __shared__ float Ws[16][68];

    const int tid = threadIdx.x;
    const int tx  = tid & 15;
    const int ty  = tid >> 4;
    const int m0  = blockIdx.y * 64;
    const int n0  = blockIdx.x * 64;
    const int lrow = tid >> 2;
    const int lk   = (tid & 3) * 4;

    float acc[4][4] = {};

    for (int kt = 0; kt < EMB; kt += 16) {
        float4 av = *(const float4*)&A[(size_t)(m0 + lrow) * EMB + kt + lk];
        float4 wv = *(const float4*)&W[(size_t)(n0 + lrow) * EMB + kt + lk];
        As[lk + 0][lrow] = av.x; As[lk + 1][lrow] = av.y;
        As[lk + 2][lrow] = av.z; As[lk + 3][lrow] = av.w;
        Ws[lk + 0][lrow] = wv.x; Ws[lk + 1][lrow] = wv.y;
        Ws[lk + 2][lrow] = wv.z; Ws[lk + 3][lrow] = wv.w;
        __syncthreads();
        #pragma unroll
        for (int kk = 0; kk < 16; ++kk) {
            float4 a = *(const float4*)&As[kk][ty * 4];
            float4 w = *(const float4*)&Ws[kk][tx * 4];
            acc[0][0] += a.x * w.x; acc[0][1] += a.x * w.y;
            acc[0][2] += a.x * w.z; acc[0][3] += a.x * w.w;
            acc[1][0] += a.y * w.x; acc[1][1] += a.y * w.y;
            acc[1][2] += a.y * w.z; acc[1][3] += a.y * w.w;
            acc[2][0] += a.z * w.x; acc[2][1] += a.z * w.y;
            acc[2][2] += a.z * w.z; acc[2][3] += a.z * w.w;
            acc[3][0] += a.w * w.x; acc[3][1] += a.w * w.y;
            acc[3][2] += a.w * w.z; acc[3][3] += a.w * w.w;
        }
        __syncthreads();
    }

    const int n = n0 + tx * 4;
    float bias[4];
    #pragma unroll
    for (int j = 0; j < 4; ++j) bias[j] = b_ih[n + j] + b_hh[n + j];

    #pragma unroll
    for (int i = 0; i < 4; ++i) {
        const int m = m0 + ty * 4 + i;
        const int b = m >> 9;
        const int s = m & 511;
        float4 o;
        o.x = acc[i][0] + bias[0];
        o.y = acc[i][1] + bias[1];
        o.z = acc[i][2] + bias[2];
        o.w = acc[i][3] + bias[3];
        *(float4*)&out[((size_t)(s * 64 + b) << 10) + n] = o;
    }
}

// ---------------------------------------------------------------------------
// 16-lane VALU DPP sum reduction (all 16 lanes end with the group sum).
// ---------------------------------------------------------------------------
__device__ __forceinline__ float red16(float x) {
    int xi, yi;
    xi = __builtin_bit_cast(int, x);
    yi = __builtin_amdgcn_update_dpp(0, xi, 0xB1, 0xF, 0xF, true);  // quad_perm xor1
    x += __builtin_bit_cast(float, yi);
    xi = __builtin_bit_cast(int, x);
    yi = __builtin_amdgcn_update_dpp(0, xi, 0x4E, 0xF, 0xF, true);  // quad_perm xor2
    x += __builtin_bit_cast(float, yi);
    xi = __builtin_bit_cast(int, x);
    yi = __builtin_amdgcn_update_dpp(0, xi, 0x124, 0xF, 0xF, true); // row_ror:4
    x += __builtin_bit_cast(float, yi);
    xi = __builtin_bit_cast(int, x);
    yi = __builtin_amdgcn_update_dpp(0, xi, 0x128, 0xF, 0xF, true); // row_ror:8
    x += __builtin_bit_cast(float, yi);
    return x;
}

__device__ __forceinline__ void drain_vmem() {
    asm volatile("s_waitcnt vmcnt(0)" ::: "memory");
}

// 16B coherent load serviced at the device coherence point (LLC).
__device__ __forceinline__ f32x4 llc_load4(const float* p) {
    f32x4 v;
    asm volatile("global_load_dwordx4 %0, %1, off sc1"
                 : "=v"(v) : "v"(p) : "memory");
    return v;
}

// ---------------------------------------------------------------------------
// Persistent recurrence: all 512 timesteps, ZERO intra-step __syncthreads.
// The WAVE is the autonomous agent: per-wave epoch flags (128 per bg), per-
// wave private LDS staging (2 batches = 4KB, two phases per step). Release:
// h sc1-stores -> vmcnt(0) -> lane0 sets wave flag. Acquire: every lane polls
// 2 of the bg's 128 wave-flags, then stages phase A (batches 0-1), issues
// phase B loads (overlaps A compute), computes, stores. LDS reuse across
// steps is safe: a wave's own flag (in the polled set) is set only after its
// compute consumed its LDS reads (in-wave lgkmcnt ordering).
// ---------------------------------------------------------------------------
__global__ __launch_bounds__(512, 2) void rnn_persist(
    const float* __restrict__ Whh,    // HID x HID row-major
    float* __restrict__ out,          // (S, B, HID); xp in, h out (in place)
    int* __restrict__ flags)          // NBG x NPW slots x 16 ints, pre-zeroed
{
    const int tid  = threadIdx.x;
    const int wave = tid >> 6;
    const int lane = tid & 63;
    const int c    = lane & 15;        // K-chunk index (64 floats per chunk)
    const int jp   = (lane >> 4) & 3;  // j-pair within wave
    const int jt   = blockIdx.x;
    const int bg   = blockIdx.y;
    const int jbase = jt * JTILE + wave * 8 + jp * 2;
    const int k0    = c * 64;

    // --- W_hh slice -> registers, pinned (persistent across all steps) ---
    f32x4 wr0[16], wr1[16];
    #pragma unroll
    for (int kq = 0; kq < 16; ++kq) {
        wr0[kq] = *(const f32x4*)&Whh[(size_t)jbase * HID + k0 + kq * 4];
        wr1[kq] = *(const f32x4*)&Whh[(size_t)(jbase + 1) * HID + k0 + kq * 4];
    }
    #pragma unroll
    for (int kq = 0; kq < 16; ++kq) {
        asm volatile("" : "+v"(wr0[kq]));
        asm volatile("" : "+v"(wr1[kq]));
    }

    // per-wave private staging: 2 batches x 16 chunks x 16 float4 (rotated)
    __shared__ float hsf[8 * 2048];    // exactly 64 KB
    const int wbase = wave * 2048;

    int* flagbase = flags + bg * NPW * FLAG_STRIDE;
    int* myflag   = flagbase + (jt * 8 + wave) * FLAG_STRIDE;

    // staging assignment: lane handles float4 idx = i*64+lane of the 512
    // float4s of one phase (2 batches). LDS slot rotated: slot=(kq+c)&15.
    int  ldsoff[8];
    int  goffA[8];                      // float offsets (fit 32-bit)
    #pragma unroll
    for (int i = 0; i < 8; ++i) {
        const int idx  = i * 64 + lane;
        const int bloc = idx >> 8;
        const int r    = idx & 255;
        const int cc   = r >> 4;
        const int kq   = r & 15;
        ldsoff[i] = wbase + bloc * 1024 + cc * 64 + (((kq + cc) & 15) << 2);
        goffA[i]  = (bg * BTILE + bloc) * HID + r * 4;
    }
    // rotated read-slot byte offsets for the compute loop
    int so[16];
    #pragma unroll
    for (int kq = 0; kq < 16; ++kq) so[kq] = (((kq + c) & 15) << 2);

    // this lane's output slot (valid when c < 8): b = c>>1, j = jbase + (c&1)
    const int ob = c >> 1;
    const size_t oaddr = (size_t)(bg * BTILE + ob) * HID + (jbase + (c & 1));

    // --- t = 0: h0 = tanh(xp) --- (wave-autonomous)
    if (c < 8) {
        float h0 = tanhf(out[oaddr]);
        __hip_atomic_store(&out[oaddr], h0, __ATOMIC_RELAXED,
                           __HIP_MEMORY_SCOPE_AGENT);
    }
    drain_vmem();
    if (lane == 0) {
        __hip_atomic_store(myflag, 1, __ATOMIC_RELAXED,
                           __HIP_MEMORY_SCOPE_AGENT);
    }

    // --- t = 1 .. SEQ-1 ---
    for (int t = 1; t < SEQ; ++t) {
        float* cur        = out + (size_t)t * (BATCH * HID);
        const float* prev = cur - (BATCH * HID);

        // prefetch xp (only this wave ever touches this slot)
        float xp = 0.f;
        if (c < 8) xp = cur[oaddr];

        // acquire: wait for all 128 producer waves of this bg
        {
            const int* f0p = flagbase + lane * FLAG_STRIDE;
            const int* f1p = flagbase + (64 + lane) * FLAG_STRIDE;
            for (;;) {
                int f0 = __hip_atomic_load(f0p, __ATOMIC_RELAXED,
                                           __HIP_MEMORY_SCOPE_AGENT);
                int f1 = __hip_atomic_load(f1p, __ATOMIC_RELAXED,
                                           __HIP_MEMORY_SCOPE_AGENT);
                if (__all(f0 >= t && f1 >= t)) break;
                __builtin_amdgcn_s_sleep(1);
            }
        }

        float acc[4][2];

        // ---- phase A: stage batches 0-1 ----
        f32x4 hv[8];
        #pragma unroll
        for (int i = 0; i < 8; ++i) hv[i] = llc_load4(prev + goffA[i]);
        drain_vmem();                       // A loads (and xp) complete
        #pragma unroll
        for (int i = 0; i < 8; ++i) *(f32x4*)&hsf[ldsoff[i]] = hv[i];

        // ---- issue phase B loads (batches 2-3), overlap with A compute ----
        f32x4 hw[8];
        #pragma unroll
        for (int i = 0; i < 8; ++i) hw[i] = llc_load4(prev + goffA[i] + 2048);

        // ---- compute phase A ----
        #pragma unroll
        for (int bloc = 0; bloc < 2; ++bloc) {
            const float* base = &hsf[wbase + bloc * 1024 + c * 64];
            f32x4 s0 = {0.f, 0.f, 0.f, 0.f};
            f32x4 s1 = {0.f, 0.f, 0.f, 0.f};
            #pragma unroll
            for (int kq = 0; kq < 16; ++kq) {
                f32x4 h4 = *(const f32x4*)&base[so[kq]];
                s0 += h4 * wr0[kq];
                s1 += h4 * wr1[kq];
            }
            acc[bloc][0] = (s0.x + s0.y) + (s0.z + s0.w);
            acc[bloc][1] = (s1.x + s1.y) + (s1.z + s1.w);
        }

        // ---- phase B: write + compute (WAR on LDS is in-wave lgkm-ordered) ----
        drain_vmem();                       // B loads complete
        #pragma unroll
        for (int i = 0; i < 8; ++i) *(f32x4*)&hsf[ldsoff[i]] = hw[i];

        #pragma unroll
        for (int bloc = 0; bloc < 2; ++bloc) {
            const float* base = &hsf[wbase + bloc * 1024 + c * 64];
            f32x4 s0 = {0.f, 0.f, 0.f, 0.f};
            f32x4 s1 = {0.f, 0.f, 0.f, 0.f};
            #pragma unroll
            for (int kq = 0; kq < 16; ++kq) {
                f32x4 h4 = *(const f32x4*)&base[so[kq]];
                s0 += h4 * wr0[kq];
                s1 += h4 * wr1[kq];
            }
            acc[2 + bloc][0] = (s0.x + s0.y) + (s0.z + s0.w);
            acc[2 + bloc][1] = (s1.x + s1.y) + (s1.z + s1.w);
        }

        // K-reduce across the 16 lanes of each jp-group (VALU DPP tree)
        #pragma unroll
        for (int b = 0; b < 4; ++b) {
            acc[b][0] = red16(acc[b][0]);
            acc[b][1] = red16(acc[b][1]);
        }

        // lane c<8 writes output (b = c>>1, jj = c&1)
        float vb0 = (c & 1) ? acc[0][1] : acc[0][0];
        float vb1 = (c & 1) ? acc[1][1] : acc[1][0];
        float vb2 = (c & 1) ? acc[2][1] : acc[2][0];
        float vb3 = (c & 1) ? acc[3][1] : acc[3][0];
        float vlo = (c & 2) ? vb1 : vb0;
        float vhi = (c & 2) ? vb3 : vb2;
        float v   = (c & 4) ? vhi : vlo;
        if (c < 8) {
            float hv2 = tanhf(xp + v);
            __hip_atomic_store(&cur[oaddr], hv2, __ATOMIC_RELAXED,
                               __HIP_MEMORY_SCOPE_AGENT);
        }

        drain_vmem();      // wave's h(t) stores are at the LLC
        if (lane == 0) {
            __hip_atomic_store(myflag, t + 1, __ATOMIC_RELAXED,
                               __HIP_MEMORY_SCOPE_AGENT);
        }
    }
}

// ---------------------------------------------------------------------------
extern "C" void kernel_launch(void* const* d_in, const int* in_sizes, int n_in,
                              void* d_out, int out_size, void* d_ws, size_t ws_size,
                              hipStream_t stream) {
    const float* embeds = (const float*)d_in[0];
    const float* W_ih   = (const float*)d_in[1];
    const float* W_hh   = (const float*)d_in[2];
    const float* b_ih   = (const float*)d_in[3];
    const float* b_hh   = (const float*)d_in[4];
    float* out = (float*)d_out;

    (void)in_sizes; (void)n_in; (void)out_size; (void)ws_size;

    // zero the epoch flags (graph-captured -> re-zeroed every replay)
    hipMemsetAsync(d_ws, 0, NBG * NPW * FLAG_STRIDE * sizeof(int), stream);

    // Phase 1: x_proj for all timesteps, written into d_out at [s][b][:]
    dim3 gA(HID / 64, (BATCH * SEQ) / 64);
    xproj_gemm<<<gA, 256, 0, stream>>>(embeds, W_ih, b_ih, b_hh, out);

    // Phase 2: persistent recurrence (one launch, per-wave flag-pipelined)
    dim3 gR(NJT, NBG);
    rnn_persist<<<gR, 512, 0, stream>>>(W_hh, out, (int*)d_ws);
}

// Round 9
// 2573.520 us; speedup vs baseline: 1.8245x; 1.8245x over previous
//
#include <hip/hip_runtime.h>
#include <math.h>

#define EMB   1024
#define HID   1024
#define BATCH   64
#define SEQ    512

#define NBG    16   // batch groups
#define BTILE   4   // batches per group (NBG*BTILE = 64)
#define NJT    16   // j-tiles (producer WGs per batch group)
#define JTILE  64   // j per tile (NJT*JTILE = 1024)

#define SLOT  65536 // floats per exchange slot (64 x 1024); 2 slots in d_ws

typedef float f32x4 __attribute__((ext_vector_type(4)));

// ---------------------------------------------------------------------------
// Kernel A: x_proj GEMM.  out[(s*64+b)*1024 + n] = sum_k embeds[b][s][k]*W_ih[n][k]
//                                                  + b_ih[n] + b_hh[n]
// ---------------------------------------------------------------------------
__global__ __launch_bounds__(256) void xproj_gemm(
    const float* __restrict__ A,
    const float* __restrict__ W,
    const float* __restrict__ b_ih,
    const float* __restrict__ b_hh,
    float* __restrict__ out)
{
    __shared__ float As[16][68];
    __shared__ float Ws[16][68];

    const int tid = threadIdx.x;
    const int tx  = tid & 15;
    const int ty  = tid >> 4;
    const int m0  = blockIdx.y * 64;
    const int n0  = blockIdx.x * 64;
    const int lrow = tid >> 2;
    const int lk   = (tid & 3) * 4;

    float acc[4][4] = {};

    for (int kt = 0; kt < EMB; kt += 16) {
        float4 av = *(const float4*)&A[(size_t)(m0 + lrow) * EMB + kt + lk];
        float4 wv = *(const float4*)&W[(size_t)(n0 + lrow) * EMB + kt + lk];
        As[lk + 0][lrow] = av.x; As[lk + 1][lrow] = av.y;
        As[lk + 2][lrow] = av.z; As[lk + 3][lrow] = av.w;
        Ws[lk + 0][lrow] = wv.x; Ws[lk + 1][lrow] = wv.y;
        Ws[lk + 2][lrow] = wv.z; Ws[lk + 3][lrow] = wv.w;
        __syncthreads();
        #pragma unroll
        for (int kk = 0; kk < 16; ++kk) {
            float4 a = *(const float4*)&As[kk][ty * 4];
            float4 w = *(const float4*)&Ws[kk][tx * 4];
            acc[0][0] += a.x * w.x; acc[0][1] += a.x * w.y;
            acc[0][2] += a.x * w.z; acc[0][3] += a.x * w.w;
            acc[1][0] += a.y * w.x; acc[1][1] += a.y * w.y;
            acc[1][2] += a.y * w.z; acc[1][3] += a.y * w.w;
            acc[2][0] += a.z * w.x; acc[2][1] += a.z * w.y;
            acc[2][2] += a.z * w.z; acc[2][3] += a.z * w.w;
            acc[3][0] += a.w * w.x; acc[3][1] += a.w * w.y;
            acc[3][2] += a.w * w.z; acc[3][3] += a.w * w.w;
        }
        __syncthreads();
    }

    const int n = n0 + tx * 4;
    float bias[4];
    #pragma unroll
    for (int j = 0; j < 4; ++j) bias[j] = b_ih[n + j] + b_hh[n + j];

    #pragma unroll
    for (int i = 0; i < 4; ++i) {
        const int m = m0 + ty * 4 + i;
        const int b = m >> 9;
        const int s = m & 511;
        float4 o;
        o.x = acc[i][0] + bias[0];
        o.y = acc[i][1] + bias[1];
        o.z = acc[i][2] + bias[2];
        o.w = acc[i][3] + bias[3];
        *(float4*)&out[((size_t)(s * 64 + b) << 10) + n] = o;
    }
}

// ---------------------------------------------------------------------------
// 16-lane VALU DPP sum reduction (all 16 lanes end with the group sum).
// ---------------------------------------------------------------------------
__device__ __forceinline__ float red16(float x) {
    int xi, yi;
    xi = __builtin_bit_cast(int, x);
    yi = __builtin_amdgcn_update_dpp(0, xi, 0xB1, 0xF, 0xF, true);  // quad_perm xor1
    x += __builtin_bit_cast(float, yi);
    xi = __builtin_bit_cast(int, x);
    yi = __builtin_amdgcn_update_dpp(0, xi, 0x4E, 0xF, 0xF, true);  // quad_perm xor2
    x += __builtin_bit_cast(float, yi);
    xi = __builtin_bit_cast(int, x);
    yi = __builtin_amdgcn_update_dpp(0, xi, 0x124, 0xF, 0xF, true); // row_ror:4
    x += __builtin_bit_cast(float, yi);
    xi = __builtin_bit_cast(int, x);
    yi = __builtin_amdgcn_update_dpp(0, xi, 0x128, 0xF, 0xF, true); // row_ror:8
    x += __builtin_bit_cast(float, yi);
    return x;
}

// SYNCHRONOUS 16B coherent load from the coherence point (LLC). The waitcnt
// is INSIDE the asm: the compiler does not know an asm global_load writes %0
// asynchronously, so without this the consumer reads garbage registers
// (round-8 failure mode).
__device__ __forceinline__ f32x4 llc_load4_sync(const float* p) {
    f32x4 v;
    asm volatile("global_load_dwordx4 %0, %1, off sc1\n\t"
                 "s_waitcnt vmcnt(0)"
                 : "=&v"(v) : "v"(p) : "memory");
    return v;
}

// Paired variant: issue both loads, single wait (halves the poll latency).
__device__ __forceinline__ void llc_load4x2_sync(const float* p0, const float* p1,
                                                 f32x4& a, f32x4& b) {
    asm volatile("global_load_dwordx4 %0, %2, off sc1\n\t"
                 "global_load_dwordx4 %1, %3, off sc1\n\t"
                 "s_waitcnt vmcnt(0)"
                 : "=&v"(a), "=&v"(b) : "v"(p0), "v"(p1) : "memory");
}

__device__ __forceinline__ bool inrange4(f32x4 v, float lo, float hi) {
    return v.x >= lo && v.x <= hi && v.y >= lo && v.y <= hi &&
           v.z >= lo && v.z <= hi && v.w >= lo && v.w <= hi;
}

// ---------------------------------------------------------------------------
// Persistent recurrence with VALUE-TAGGED exchange (data-as-flag).
// Producers store h + 4*(t%4) into exch slot t%2 (agent-scope sc1 stores).
// |h| <= 1 so tag ranges [-1,1],[3,5],[7,9],[11,13] are disjoint; the 0x7F
// memset sentinel (3.4e38) is outside all of them. Consumers poll the data
// itself with SYNCHRONOUS sc1 loads: a 16B chunk is ready when all 4 dwords
// are in the expected range. Soundness of tag period 4 over 2 slots: a
// consumer at step x forces every producer >= x-2 (induction from sentinel
// base); the only reachable slot states at consume are h(x-1) (accept) and
// h(x-3) (tag differs by 2 -> block). LDS double-buffered; one barrier/step.
// ---------------------------------------------------------------------------
__global__ __launch_bounds__(512, 2) void rnn_persist(
    const float* __restrict__ Whh,    // HID x HID row-major
    float* __restrict__ out,          // (S, B, HID); xp in, h out (in place)
    float* __restrict__ exch)         // 2*SLOT floats, 0x7F-poisoned per launch
{
    const int tid  = threadIdx.x;
    const int wave = tid >> 6;
    const int lane = tid & 63;
    const int c    = lane & 15;        // K-chunk index (64 floats per chunk)
    const int jp   = (lane >> 4) & 3;  // j-pair within wave
    const int jt   = blockIdx.x;
    const int bg   = blockIdx.y;
    const int jbase = jt * JTILE + wave * 8 + jp * 2;
    const int k0    = c * 64;

    // --- W_hh slice -> registers, pinned (persistent across all steps) ---
    f32x4 wr0[16], wr1[16];
    #pragma unroll
    for (int kq = 0; kq < 16; ++kq) {
        wr0[kq] = *(const f32x4*)&Whh[(size_t)jbase * HID + k0 + kq * 4];
        wr1[kq] = *(const f32x4*)&Whh[(size_t)(jbase + 1) * HID + k0 + kq * 4];
    }
    #pragma unroll
    for (int kq = 0; kq < 16; ++kq) {
        asm volatile("" : "+v"(wr0[kq]));
        asm volatile("" : "+v"(wr1[kq]));
    }

    // double-buffered h staging: 2 x (4 batches x 16 chunks x 68 floats)
    __shared__ float hsf[2 * 4352];

    // cooperative staging: thread handles float4 idx tid and tid+512 of the
    // 1024 float4s (4 rows x 1024 floats) of its bg slice
    const int p0 = tid, p1 = tid + 512;
    const int b0i = p0 >> 8, r0 = p0 & 255;
    const int b1i = p1 >> 8, r1 = p1 & 255;
    const int exoff0 = (bg * BTILE + b0i) * HID + r0 * 4;
    const int exoff1 = (bg * BTILE + b1i) * HID + r1 * 4;
    const int ldo0 = b0i * 1088 + (r0 >> 4) * 68 + (r0 & 15) * 4;
    const int ldo1 = b1i * 1088 + (r1 >> 4) * 68 + (r1 & 15) * 4;

    // this lane's output slot (valid when c < 8): b = c>>1, j = jbase + (c&1)
    const int ob   = c >> 1;
    const int oidx = (bg * BTILE + ob) * HID + (jbase + (c & 1));

    // --- t = 0: h0 = tanh(xp); publish tagged (tag 0) to exch slot 0 ---
    if (c < 8) {
        float h0 = tanhf(out[oidx]);
        out[oidx] = h0;                               // plain cached store
        __hip_atomic_store(&exch[oidx], h0, __ATOMIC_RELAXED,
                           __HIP_MEMORY_SCOPE_AGENT); // sc1 -> LLC
    }

    // --- t = 1 .. SEQ-1 ---
    for (int t = 1; t < SEQ; ++t) {
        float* cur = out + (size_t)t * (BATCH * HID);

        // prefetch xp early (off the critical path; consumed after compute)
        float xp = 0.f;
        if (c < 8) xp = cur[oidx];

        // ---- poll + fetch h(t-1): the load IS the flag ----
        const float off = 4.0f * (float)((t - 1) & 3);
        const float lo  = off - 1.0f, hi = off + 1.0f;
        const float* eb = exch + ((t - 1) & 1) * SLOT;

        f32x4 v0, v1;
        llc_load4x2_sync(eb + exoff0, eb + exoff1, v0, v1);
        bool ok0 = inrange4(v0, lo, hi);
        bool ok1 = inrange4(v1, lo, hi);
        while (!__all(ok0 && ok1)) {
            __builtin_amdgcn_s_sleep(1);
            if (!ok0) { v0 = llc_load4_sync(eb + exoff0); ok0 = inrange4(v0, lo, hi); }
            if (!ok1) { v1 = llc_load4_sync(eb + exoff1); ok1 = inrange4(v1, lo, hi); }
        }
        v0 -= off;                       // strip the tag
        v1 -= off;

        const int bufb = (t & 1) * 4352;
        *(f32x4*)&hsf[bufb + ldo0] = v0;
        *(f32x4*)&hsf[bufb + ldo1] = v1;
        __syncthreads();                 // staging complete (only barrier/step)

        // ---- compute: acc[b][jj] = partial dot over this lane's 64-k chunk ----
        float acc[4][2];
        #pragma unroll
        for (int b = 0; b < 4; ++b) {
            const f32x4* hb = (const f32x4*)&hsf[bufb + b * 1088 + c * 68];
            f32x4 s0 = {0.f, 0.f, 0.f, 0.f};
            f32x4 s1 = {0.f, 0.f, 0.f, 0.f};
            #pragma unroll
            for (int kq = 0; kq < 16; ++kq) {
                f32x4 h4 = hb[kq];
                s0 += h4 * wr0[kq];
                s1 += h4 * wr1[kq];
            }
            acc[b][0] = (s0.x + s0.y) + (s0.z + s0.w);
            acc[b][1] = (s1.x + s1.y) + (s1.z + s1.w);
        }

        // K-reduce across the 16 lanes of each jp-group (VALU DPP tree)
        #pragma unroll
        for (int b = 0; b < 4; ++b) {
            acc[b][0] = red16(acc[b][0]);
            acc[b][1] = red16(acc[b][1]);
        }

        // lane c<8 owns (b = c>>1, jj = c&1)
        float vb0 = (c & 1) ? acc[0][1] : acc[0][0];
        float vb1 = (c & 1) ? acc[1][1] : acc[1][0];
        float vb2 = (c & 1) ? acc[2][1] : acc[2][0];
        float vb3 = (c & 1) ? acc[3][1] : acc[3][0];
        float vlo = (c & 2) ? vb1 : vb0;
        float vhi = (c & 2) ? vb3 : vb2;
        float v   = (c & 4) ? vhi : vlo;
        if (c < 8) {
            float hv = tanhf(xp + v);
            cur[oidx] = hv;                              // output (plain)
            __hip_atomic_store(&exch[(t & 1) * SLOT + oidx],
                               hv + 4.0f * (float)(t & 3),
                               __ATOMIC_RELAXED, __HIP_MEMORY_SCOPE_AGENT);
        }
        // no drain, no release barrier: consumers validate by value
    }
}

// ---------------------------------------------------------------------------
extern "C" void kernel_launch(void* const* d_in, const int* in_sizes, int n_in,
                              void* d_out, int out_size, void* d_ws, size_t ws_size,
                              hipStream_t stream) {
    const float* embeds = (const float*)d_in[0];
    const float* W_ih   = (const float*)d_in[1];
    const float* W_hh   = (const float*)d_in[2];
    const float* b_ih   = (const float*)d_in[3];
    const float* b_hh   = (const float*)d_in[4];
    float* out = (float*)d_out;

    (void)in_sizes; (void)n_in; (void)out_size; (void)ws_size;

    // poison exchange buffer to sentinel 0x7F7F7F7F (=3.4e38, outside every
    // tag range). Captured in the graph -> re-poisoned every replay.
    hipMemsetAsync(d_ws, 0x7F, 2 * SLOT * sizeof(float), stream);

    // Phase 1: x_proj for all timesteps, written into d_out at [s][b][:]
    dim3 gA(HID / 64, (BATCH * SEQ) / 64);
    xproj_gemm<<<gA, 256, 0, stream>>>(embeds, W_ih, b_ih, b_hh, out);

    // Phase 2: persistent recurrence (one launch, value-tagged pipelining)
    dim3 gR(NJT, NBG);
    rnn_persist<<<gR, 512, 0, stream>>>(W_hh, out, (float*)d_ws);
}

// Round 10
// 2570.631 us; speedup vs baseline: 1.8265x; 1.0011x over previous
//
#include <hip/hip_runtime.h>
#include <math.h>

#define EMB    1024
#define HID    1024
#define BATCH    64
#define SEQ     512

#define NBG     16   // batch groups
#define BTILE    4   // batches per group
#define NJT     16   // j-tile WGs per batch group
#define JTILE   64   // j per tile

#define SLOT   65536 // floats per exchange slot (64 x 1024); 2 slots in d_ws
#define STEPSZ 65536 // floats per timestep in out (64 x 1024)

typedef float f32x4 __attribute__((ext_vector_type(4)));

// ---------------------------------------------------------------------------
// Kernel A: x_proj GEMM (unchanged).
// ---------------------------------------------------------------------------
__global__ __launch_bounds__(256) void xproj_gemm(
    const float* __restrict__ A,
    const float* __restrict__ W,
    const float* __restrict__ b_ih,
    const float* __restrict__ b_hh,
    float* __restrict__ out)
{
    __shared__ float As[16][68];
    __shared__ float Ws[16][68];

    const int tid = threadIdx.x;
    const int tx  = tid & 15;
    const int ty  = tid >> 4;
    const int m0  = blockIdx.y * 64;
    const int n0  = blockIdx.x * 64;
    const int lrow = tid >> 2;
    const int lk   = (tid & 3) * 4;

    float acc[4][4] = {};

    for (int kt = 0; kt < EMB; kt += 16) {
        float4 av = *(const float4*)&A[(size_t)(m0 + lrow) * EMB + kt + lk];
        float4 wv = *(const float4*)&W[(size_t)(n0 + lrow) * EMB + kt + lk];
        As[lk + 0][lrow] = av.x; As[lk + 1][lrow] = av.y;
        As[lk + 2][lrow] = av.z; As[lk + 3][lrow] = av.w;
        Ws[lk + 0][lrow] = wv.x; Ws[lk + 1][lrow] = wv.y;
        Ws[lk + 2][lrow] = wv.z; Ws[lk + 3][lrow] = wv.w;
        __syncthreads();
        #pragma unroll
        for (int kk = 0; kk < 16; ++kk) {
            float4 a = *(const float4*)&As[kk][ty * 4];
            float4 w = *(const float4*)&Ws[kk][tx * 4];
            acc[0][0] += a.x * w.x; acc[0][1] += a.x * w.y;
            acc[0][2] += a.x * w.z; acc[0][3] += a.x * w.w;
            acc[1][0] += a.y * w.x; acc[1][1] += a.y * w.y;
            acc[1][2] += a.y * w.z; acc[1][3] += a.y * w.w;
            acc[2][0] += a.z * w.x; acc[2][1] += a.z * w.y;
            acc[2][2] += a.z * w.z; acc[2][3] += a.z * w.w;
            acc[3][0] += a.w * w.x; acc[3][1] += a.w * w.y;
            acc[3][2] += a.w * w.z; acc[3][3] += a.w * w.w;
        }
        __syncthreads();
    }

    const int n = n0 + tx * 4;
    float bias[4];
    #pragma unroll
    for (int j = 0; j < 4; ++j) bias[j] = b_ih[n + j] + b_hh[n + j];

    #pragma unroll
    for (int i = 0; i < 4; ++i) {
        const int m = m0 + ty * 4 + i;
        const int b = m >> 9;
        const int s = m & 511;
        float4 o;
        o.x = acc[i][0] + bias[0];
        o.y = acc[i][1] + bias[1];
        o.z = acc[i][2] + bias[2];
        o.w = acc[i][3] + bias[3];
        *(float4*)&out[((size_t)(s * 64 + b) << 10) + n] = o;
    }
}

// ---------------------------------------------------------------------------
// 16-lane VALU DPP sum reduction (all 16 lanes end with the group sum).
// ---------------------------------------------------------------------------
__device__ __forceinline__ float red16(float x) {
    int xi, yi;
    xi = __builtin_bit_cast(int, x);
    yi = __builtin_amdgcn_update_dpp(0, xi, 0xB1, 0xF, 0xF, true);  // quad_perm xor1
    x += __builtin_bit_cast(float, yi);
    xi = __builtin_bit_cast(int, x);
    yi = __builtin_amdgcn_update_dpp(0, xi, 0x4E, 0xF, 0xF, true);  // quad_perm xor2
    x += __builtin_bit_cast(float, yi);
    xi = __builtin_bit_cast(int, x);
    yi = __builtin_amdgcn_update_dpp(0, xi, 0x124, 0xF, 0xF, true); // row_ror:4
    x += __builtin_bit_cast(float, yi);
    xi = __builtin_bit_cast(int, x);
    yi = __builtin_amdgcn_update_dpp(0, xi, 0x128, 0xF, 0xF, true); // row_ror:8
    x += __builtin_bit_cast(float, yi);
    return x;
}

// ASYNC 16B coherent load (sc1, serviced at the LLC). Caller MUST
// s_waitcnt vmcnt(0) (+ sched_barrier) before reading the result.
__device__ __forceinline__ f32x4 llc_load4_async(const float* p) {
    f32x4 v;
    asm volatile("global_load_dwordx4 %0, %1, off sc1"
                 : "=&v"(v) : "v"(p) : "memory");
    return v;
}

// SYNC variant (waitcnt inside — round-8 lesson).
__device__ __forceinline__ f32x4 llc_load4_sync(const float* p) {
    f32x4 v;
    asm volatile("global_load_dwordx4 %0, %1, off sc1\n\t"
                 "s_waitcnt vmcnt(0)"
                 : "=&v"(v) : "v"(p) : "memory");
    return v;
}

// Drain vmem; sched_barrier stops the scheduler from hoisting dependent
// VALU above the wait (rule #18).
__device__ __forceinline__ void wait_vm0() {
    asm volatile("s_waitcnt vmcnt(0)" ::: "memory");
    __builtin_amdgcn_sched_barrier(0);
}

// Raw workgroup barrier draining ONLY lgkmcnt: LDS writes become visible,
// but async vmem loads stay in flight across it (unlike __syncthreads,
// which drains vmcnt(0) and would kill the prefetch pipeline).
__device__ __forceinline__ void bar_lgkm() {
    asm volatile("s_waitcnt lgkmcnt(0)\n\ts_barrier" ::: "memory");
}

__device__ __forceinline__ bool inrange4(f32x4 v, float lo, float hi) {
    return v.x >= lo && v.x <= hi && v.y >= lo && v.y <= hi &&
           v.z >= lo && v.z <= hi && v.w >= lo && v.w <= hi;
}

// ---------------------------------------------------------------------------
// Persistent recurrence, PER-BATCH software pipeline (4 sub-iterations/step).
// The 4 batches of a bg are independent chains; value-tagged exchange
// (tag = 4*(t%4), slot = t%2, 0x7F sentinel) per batch — same induction as
// round 9, applied per batch. Per sub-iteration:
//   wait vm0 -> store pending h (prev iter's result; queue is store-free at
//   the wait) -> validate prefetched data (sync-retry on miss) -> stage to
//   LDS (tag stripped) -> issue async prefetch for next batch -> raw
//   lgkm-barrier -> compute batch b -> result held in regs (stored next iter).
// Prefetch-to-use distance (barrier+compute) hides most of the LLC RT.
// ---------------------------------------------------------------------------
__global__ __launch_bounds__(512, 2) void rnn_persist(
    const float* __restrict__ Whh,    // HID x HID row-major
    float* __restrict__ out,          // (S, B, HID); xp in, h out (in place)
    float* __restrict__ exch)         // 2*SLOT floats, 0x7F-poisoned per launch
{
    const int tid  = threadIdx.x;
    const int wave = tid >> 6;
    const int lane = tid & 63;
    const int c    = lane & 15;          // K-chunk index (64 floats per chunk)
    const int jt   = blockIdx.x;
    const int bg   = blockIdx.y;
    const int jbase = jt * JTILE + wave * 8 + ((lane >> 4) & 3) * 2;
    const int k0    = c * 64;

    // --- W_hh slice -> registers, pinned ---
    f32x4 wr0[16], wr1[16];
    #pragma unroll
    for (int kq = 0; kq < 16; ++kq) {
        wr0[kq] = *(const f32x4*)&Whh[(size_t)jbase * HID + k0 + kq * 4];
        wr1[kq] = *(const f32x4*)&Whh[(size_t)(jbase + 1) * HID + k0 + kq * 4];
    }
    #pragma unroll
    for (int kq = 0; kq < 16; ++kq) {
        asm volatile("" : "+v"(wr0[kq]));
        asm volatile("" : "+v"(wr1[kq]));
    }

    // double-buffered single-batch staging: 2 x (16 chunks x 68 floats)
    __shared__ float hsf[2 * 1088];

    // staging role: threads 0..255 load float4 f of the current batch slice
    const bool have  = (tid < 256);
    const int  fidx  = tid & 255;
    const int  ldoff = (fidx >> 4) * 68 + (fidx & 15) * 4;
    const int  gq    = fidx * 4;

    // output ownership: lane c<8 owns (batch=c>>1, j=jbase+(c&1))
    const int jout  = jbase + (c & 1);
    const int mybat = c >> 1;                                  // valid if c<8
    const int orow  = (bg * BTILE + mybat) * HID + jout;       // row index

    // --- t = 0: h0 = tanh(xp); publish tag 0 into slot 0 ---
    if (c < 8) {
        float h0 = tanhf(out[orow]);
        out[orow] = h0;
        __hip_atomic_store(&exch[orow], h0, __ATOMIC_RELAXED,
                           __HIP_MEMORY_SCOPE_AGENT);
    }

    // prime: xp(1) and prefetch (t=1, b=0)
    float xp = 0.f;
    if (c < 8) xp = out[(size_t)STEPSZ + orow];

    f32x4 pf = {0.f, 0.f, 0.f, 0.f};
    if (have) pf = llc_load4_async(exch + (bg * BTILE + 0) * HID + gq);

    float pend = 0.f;   // fully-computed h awaiting store (owning lanes)

    for (int t = 1; t < SEQ; ++t) {
        #pragma unroll
        for (int b = 0; b < 4; ++b) {
            const int   tp    = t - 1;
            const float off   = 4.0f * (float)(tp & 3);
            const float lo    = off - 1.0f, hi = off + 1.0f;
            const float* ebase = exch + (tp & 1) * SLOT + (bg * BTILE + b) * HID;

            // ---- V: drain vmem (prefetch + xp; prev stores long acked) ----
            wait_vm0();

            // store pending h from the previous sub-iteration
            {
                const int bprev = (b == 0) ? 3 : (b - 1);
                const int tprev = (b == 0) ? (t - 1) : t;
                if (!(b == 0 && t == 1)) {
                    if (mybat == bprev) {   // implies c<8
                        const int oi = (bg * BTILE + bprev) * HID + jout;
                        out[(size_t)tprev * STEPSZ + oi] = pend;
                        __hip_atomic_store(&exch[(tprev & 1) * SLOT + oi],
                                           pend + 4.0f * (float)(tprev & 3),
                                           __ATOMIC_RELAXED,
                                           __HIP_MEMORY_SCOPE_AGENT);
                    }
                }
            }

            // validate prefetched data; sync-retry only invalid lanes
            bool ok = !have || inrange4(pf, lo, hi);
            while (!__all(ok)) {
                if (!ok) {
                    pf = llc_load4_sync(ebase + gq);
                    ok = inrange4(pf, lo, hi);
                }
            }

            // stage (tag stripped) into buffer b&1
            if (have) *(f32x4*)&hsf[(b & 1) * 1088 + ldoff] = pf - off;

            // issue async prefetch for the next sub-iteration
            {
                const int bn = (b + 1) & 3;
                const int tn = (b == 3) ? (t + 1) : t;
                if (tn < SEQ) {
                    const float* nb =
                        exch + ((tn - 1) & 1) * SLOT + (bg * BTILE + bn) * HID;
                    if (have) pf = llc_load4_async(nb + gq);
                }
            }

            bar_lgkm();   // staging visible; prefetch stays in flight

            // ---- C: compute batch b ----
            {
                const float* base = &hsf[(b & 1) * 1088 + c * 68];
                f32x4 s0 = {0.f, 0.f, 0.f, 0.f};
                f32x4 s1 = {0.f, 0.f, 0.f, 0.f};
                #pragma unroll
                for (int kq = 0; kq < 16; ++kq) {
                    f32x4 h4 = *(const f32x4*)&base[kq * 4];
                    s0 += h4 * wr0[kq];
                    s1 += h4 * wr1[kq];
                }
                float a0 = (s0.x + s0.y) + (s0.z + s0.w);
                float a1 = (s1.x + s1.y) + (s1.z + s1.w);
                a0 = red16(a0);
                a1 = red16(a1);
                if (mybat == b) {                      // implies c<8
                    pend = tanhf(xp + ((c & 1) ? a1 : a0));
                }
            }

            // xp for step t+1 (placed AFTER compute: xp(t) consumed above)
            if (b == 3 && t + 1 < SEQ) {
                if (c < 8) xp = out[(size_t)(t + 1) * STEPSZ + orow];
            }
        }
    }

    // pipeline drain: h(SEQ-1, batch 3) still pending
    if (mybat == 3) {
        out[(size_t)(SEQ - 1) * STEPSZ + (bg * BTILE + 3) * HID + jout] = pend;
    }
}

// ---------------------------------------------------------------------------
extern "C" void kernel_launch(void* const* d_in, const int* in_sizes, int n_in,
                              void* d_out, int out_size, void* d_ws, size_t ws_size,
                              hipStream_t stream) {
    const float* embeds = (const float*)d_in[0];
    const float* W_ih   = (const float*)d_in[1];
    const float* W_hh   = (const float*)d_in[2];
    const float* b_ih   = (const float*)d_in[3];
    const float* b_hh   = (const float*)d_in[4];
    float* out = (float*)d_out;

    (void)in_sizes; (void)n_in; (void)out_size; (void)ws_size;

    // poison exchange buffer to sentinel 0x7F7F7F7F (outside every tag range);
    // captured in the graph -> re-poisoned every replay.
    hipMemsetAsync(d_ws, 0x7F, 2 * SLOT * sizeof(float), stream);

    // Phase 1: x_proj for all timesteps, written into d_out at [s][b][:]
    dim3 gA(HID / 64, (BATCH * SEQ) / 64);
    xproj_gemm<<<gA, 256, 0, stream>>>(embeds, W_ih, b_ih, b_hh, out);

    // Phase 2: persistent recurrence (per-batch pipelined, value-tagged)
    dim3 gR(NJT, NBG);
    rnn_persist<<<gR, 512, 0, stream>>>(W_hh, out, (float*)d_ws);
}